// Round 9
// baseline (185.851 us; speedup 1.0000x reference)
//
#include <hip/hip_runtime.h>
#include <math.h>

#define EPS_N 1e-12f
#define MARGIN 0.3f
#define INF_BITS 0x7f800000u
#define NCLS 128     // label space (randint(0,128))
#define D 512
#define PADR 256     // padded rows after fh so banded staging can over-read safely

typedef __attribute__((ext_vector_type(8))) short short8;   // 8 bf16 = 4 VGPRs
typedef __attribute__((ext_vector_type(4))) float float4v;  // MFMA 16x16 accum

__device__ __forceinline__ unsigned short f2bf(float f) {   // RNE bf16
    unsigned u = __float_as_uint(f);
    u += 0x7fff + ((u >> 16) & 1);
    return (unsigned short)(u >> 16);
}
__device__ __forceinline__ void gl16(const void* g, void* l) {
    // 16B async global->LDS; global addr per-lane, LDS dest = uniform base + lane*16
    __builtin_amdgcn_global_load_lds((const __attribute__((address_space(1))) void*)g,
                                     (__attribute__((address_space(3))) void*)l, 16, 0, 0);
}

// ---------------------------------------------------------------------------
// K0: one-block bucketing, coalesced-metadata version (R8 post-mortem: node
// overhead ~7-10 us dominates small kernels; consolidate). Phases:
//   1) LDS histogram  2) LDS scan  3) per-slot metadata fills, COALESCED via
//   binary-search class-of-slot  4) pos[i] scatter via LDS offset atomics.
// Also zeroes the done counter for minsh's fused tail.
// ---------------------------------------------------------------------------
__global__ __launch_bounds__(1024) void k_bucket(const int* __restrict__ lab, int Bn,
        int* __restrict__ pos, int* __restrict__ labp,
        int* __restrict__ cstart_g, int* __restrict__ ccnt_g,
        float* __restrict__ meanpos, float* __restrict__ pcinv,
        int* __restrict__ poscnt, unsigned* __restrict__ minbits,
        unsigned* __restrict__ done) {
    __shared__ int cnt[NCLS], cs[NCLS + 1], off[NCLS], sa[NCLS], sb[NCLS];
    int tid = threadIdx.x;
    if (tid == 0) done[0] = 0u;
    if (tid < NCLS) cnt[tid] = 0;
    __syncthreads();
    for (int i = tid; i < Bn; i += 1024) atomicAdd(&cnt[lab[i] & (NCLS - 1)], 1);
    __syncthreads();
    if (tid < NCLS) sa[tid] = cnt[tid];
    __syncthreads();
    int* src = sa; int* dst = sb;
    for (int ofs = 1; ofs < NCLS; ofs <<= 1) {          // Hillis-Steele inclusive
        if (tid < NCLS) dst[tid] = src[tid] + ((tid >= ofs) ? src[tid - ofs] : 0);
        __syncthreads();
        int* t = src; src = dst; dst = t;
    }
    if (tid < NCLS) {
        int ex = src[tid] - cnt[tid];                   // exclusive
        cs[tid] = ex;
        off[tid] = ex;
        cstart_g[tid] = ex;
        ccnt_g[tid] = cnt[tid];
    }
    if (tid == 0) cs[NCLS] = Bn;
    __syncthreads();
    // coalesced per-slot metadata: class(p) = largest l with cs[l] <= p
    for (int p = tid; p < Bn; p += 1024) {
        int lo = 0, hi = NCLS - 1;
        #pragma unroll
        for (int s = 0; s < 7; ++s) {
            int mid = (lo + hi + 1) >> 1;
            if (cs[mid] <= p) lo = mid; else hi = mid - 1;
        }
        int l = lo, m = cnt[l];
        labp[p] = l;
        poscnt[p] = m;
        pcinv[p] = 1.0f / (float)m;
        meanpos[p] = 0.f;          // accumulates raw dist-sums (posband3)
        minbits[p] = INF_BITS;
    }
    // pos scatter (reads coalesced; only pos[] store is scattered-by-class)
    for (int i = tid; i < Bn; i += 1024) {
        int l = lab[i] & (NCLS - 1);
        pos[i] = atomicAdd(&off[l], 1);
    }
}

// ---------------------------------------------------------------------------
// K1: normalize; one wave per row, no __syncthreads. Lane L owns elements
// [L*8, L*8+8); butterfly reduce; one 16 B bf16 store per lane to permuted slot.
// ---------------------------------------------------------------------------
__global__ __launch_bounds__(256) void k_normalize(const float* __restrict__ x,
        const int* __restrict__ pos, unsigned short* __restrict__ fh,
        float* __restrict__ sqp) {
    int w = threadIdx.x >> 6, L = threadIdx.x & 63;
    int row = blockIdx.x * 4 + w;
    const float* xr = x + (size_t)row * D + L * 8;
    float4 a = *(const float4*)xr;
    float4 b = *(const float4*)(xr + 4);
    float ss = a.x * a.x;
    ss = fmaf(a.y, a.y, ss); ss = fmaf(a.z, a.z, ss); ss = fmaf(a.w, a.w, ss);
    ss = fmaf(b.x, b.x, ss); ss = fmaf(b.y, b.y, ss);
    ss = fmaf(b.z, b.z, ss); ss = fmaf(b.w, b.w, ss);
    #pragma unroll
    for (int off = 32; off; off >>= 1) ss += __shfl_xor(ss, off, 64);
    float inv = 1.0f / fmaxf(sqrtf(ss), EPS_N);
    int prow = pos[row];
    if (L == 0) sqp[prow] = ss * inv * inv;
    ushort4 h0, h1;
    h0.x = f2bf(a.x * inv); h0.y = f2bf(a.y * inv);
    h0.z = f2bf(a.z * inv); h0.w = f2bf(a.w * inv);
    h1.x = f2bf(b.x * inv); h1.y = f2bf(b.y * inv);
    h1.z = f2bf(b.z * inv); h1.w = f2bf(b.w * inv);
    unsigned short* dst = fh + (size_t)prow * D + L * 8;
    *(ushort4*)dst = h0;
    *(ushort4*)(dst + 4) = h1;
}

// ---------------------------------------------------------------------------
// K2: banded positive stats v3 (unchanged from R7/R8). One block per 16-row
// group (512 blocks, 2/CU), full class window, BK=128.
// ---------------------------------------------------------------------------
__global__ __launch_bounds__(256) void k_posband3(
    const unsigned short* __restrict__ fh, const float* __restrict__ sqp,
    const int* __restrict__ labp, const int* __restrict__ cstart_g,
    const int* __restrict__ ccnt_g, float* __restrict__ meanpos, int Bn)
{
    __shared__ unsigned short SA[16 * 128];    // 4 KB per K-chunk
    __shared__ unsigned short SB[128 * 128];   // 32 KB per K-chunk
    __shared__ float sqr[16], rs[16];
    __shared__ int labr[16];
    __shared__ float sqc[128];
    __shared__ int labc[128];

    const int r0 = blockIdx.x * 16;
    const int tid = threadIdx.x, w = tid >> 6, L = tid & 63;
    const int lm = L & 15, ls = L >> 4;
    const int srow = L >> 4;      // 0..3 rows per gl16 group
    const int sseg = L & 15;      // 16-B seg slot within a 256 B row

    if (tid < 16) {
        labr[tid] = labp[r0 + tid];
        sqr[tid]  = sqp[r0 + tid];
        rs[tid]   = 0.f;
    }
    __syncthreads();
    const int c0 = cstart_g[labr[0]];
    const int c1 = cstart_g[labr[15]] + ccnt_g[labr[15]];

    for (int cc0 = c0; cc0 < c1; cc0 += 128) {
        __syncthreads();
        if (tid < 128) {
            int q = cc0 + tid;
            if (q < Bn) { sqc[tid] = sqp[q]; labc[tid] = labp[q]; }
            else        { sqc[tid] = 0.f;    labc[tid] = -1; }
        }
        float4v acc[2];
        acc[0] = (float4v){0.f, 0.f, 0.f, 0.f};
        acc[1] = (float4v){0.f, 0.f, 0.f, 0.f};

        for (int k0 = 0; k0 < D; k0 += 128) {
            __syncthreads();
            {   // SA: wave w stages rows w*4 .. w*4+3 (one gl16)
                int rmat = w * 4 + srow;
                int seg = sseg ^ (rmat & 15);
                gl16(fh + (size_t)(r0 + rmat) * D + k0 + seg * 8, &SA[(w * 4) * 128]);
            }
            #pragma unroll
            for (int it = 0; it < 8; ++it) {  // SB: 32 gl16 across 4 waves
                int rmat = it * 16 + w * 4 + srow;          // 0..127 (may over-read pad)
                int seg = sseg ^ (rmat & 15);
                gl16(fh + (size_t)(cc0 + rmat) * D + k0 + seg * 8,
                     &SB[(size_t)(it * 16 + w * 4) * 128]);
            }
            __syncthreads();
            #pragma unroll
            for (int h = 0; h < 4; ++h) {      // K=128 in 4 MFMA sub-steps
                int ra = lm;
                short8 af = *(const short8*)&SA[ra * 128 + (((h * 4 + ls) ^ (ra & 15))) * 8];
                #pragma unroll
                for (int ct = 0; ct < 2; ++ct) {
                    int rb = w * 32 + ct * 16 + lm;
                    short8 bf = *(const short8*)&SB[rb * 128 + (((h * 4 + ls) ^ (rb & 15))) * 8];
                    acc[ct] = __builtin_amdgcn_mfma_f32_16x16x32_bf16(af, bf, acc[ct], 0, 0, 0);
                }
            }
        }
        // epilogue: masked dist row-sums. C/D: row = ls*4+v, col = w*32+ct*16+lm
        #pragma unroll
        for (int v = 0; v < 4; ++v) {
            int ri = ls * 4 + v;
            int p = r0 + ri;
            int lr = labr[ri];
            float sr = sqr[ri];
            float sum = 0.f;
            #pragma unroll
            for (int ct = 0; ct < 2; ++ct) {
                int ci = w * 32 + ct * 16 + lm;
                int q = cc0 + ci;
                float d2 = sr + sqc[ci] - 2.0f * acc[ct][v];
                float dd = (d2 > 0.f) ? sqrtf(d2) : 0.f;
                sum += ((labc[ci] == lr) && (q != p)) ? dd : 0.f;
            }
            #pragma unroll
            for (int off = 8; off; off >>= 1) sum += __shfl_xor(sum, off, 64);
            if (lm == 0) atomicAdd(&rs[ri], sum);
        }
    }
    __syncthreads();
    if (tid < 16 && rs[tid] != 0.f) atomicAdd(&meanpos[r0 + tid], rs[tid]);
}

// ---------------------------------------------------------------------------
// K3: hi-only bf16 MFMA GEMM + fused semi-hard min. New vs R8:
//  (a) XCD-contiguous tile remap: t = (b&7)*(T/8) + (b>>3) so each XCD's
//      blocks cover a contiguous triangular range (L2 locality).
//  (b) fused final reduction via done-counter, NO __threadfence (R6's wbl2
//      disaster): the pre-tail __syncthreads already drains vmcnt(0), so all
//      epilogue atomicMins completed at the coherence point; tail reads
//      minbits via idempotent atomicMin (cross-XCD coherent).
// ---------------------------------------------------------------------------
#define BKG 64

__global__ __launch_bounds__(256, 4) void k_minsh_mfma(
    const unsigned short* __restrict__ fh, const float* __restrict__ sqp,
    const int* __restrict__ labp, const float* __restrict__ meanpos,
    const float* __restrict__ pcinv, const int* __restrict__ poscnt,
    unsigned* __restrict__ minbits, unsigned* __restrict__ done,
    float* __restrict__ out, int Bn, int Tot)
{
    int b = blockIdx.x;
    int t = (b & 7) * (Tot >> 3) + (b >> 3);   // Tot divisible by 8 (2080)
    int rq = (int)((sqrtf(8.0f * (float)t + 1.0f) - 1.0f) * 0.5f);
    while ((rq + 1) * (rq + 2) / 2 <= t) ++rq;
    while (rq * (rq + 1) / 2 > t) --rq;
    int cq = t - rq * (rq + 1) / 2;
    const int i0 = cq * 128, j0 = rq * 128;
    const bool diag = (i0 == j0);

    __shared__ unsigned short LA[2][128 * BKG];   // 32 KB
    __shared__ float s_mp2r[128], s_mp2c[128], s_sqr[128], s_sqc[128];
    __shared__ int s_labr[128], s_labc[128];

    const int tid = threadIdx.x;
    const int w = tid >> 6, L = tid & 63;

    if (tid < 128) {
        float mp = meanpos[i0 + tid] * pcinv[i0 + tid];
        s_mp2r[tid] = mp * mp;
        s_sqr[tid]  = sqp[i0 + tid];
        s_labr[tid] = labp[i0 + tid];
    } else {
        int q = tid - 128;
        float mp = meanpos[j0 + q] * pcinv[j0 + q];
        s_mp2c[q] = mp * mp;
        s_sqc[q]  = sqp[j0 + q];
        s_labc[q] = labp[j0 + q];
    }

    const unsigned short* msrc = fh + (size_t)((w < 2) ? i0 : j0) * D;
    unsigned short* mylds = &LA[(w < 2) ? 0 : 1][(w & 1) * 64 * BKG];
    const int srow = L >> 3;
    const int sseg = L & 7;

    float4v acc[4][4];
    #pragma unroll
    for (int a = 0; a < 4; ++a)
        #pragma unroll
        for (int bq = 0; bq < 4; ++bq) acc[a][bq] = (float4v){0.f, 0.f, 0.f, 0.f};

    const int rw = (w >> 1) * 64, cw = (w & 1) * 64;
    const int lm = L & 15, ls = L >> 4;

    for (int k0 = 0; k0 < D; k0 += BKG) {
        __syncthreads();
        #pragma unroll
        for (int it = 0; it < 8; ++it) {
            int rmat = (w & 1) * 64 + it * 8 + srow;
            int seg = sseg ^ (rmat & 7);
            gl16(msrc + (size_t)rmat * D + k0 + seg * 8, mylds + it * 512);
        }
        __syncthreads();
        #pragma unroll
        for (int h = 0; h < 2; ++h) {
            short8 ah[4], bh[4];
            #pragma unroll
            for (int mi = 0; mi < 4; ++mi) {
                int r = rw + mi * 16 + lm;
                int slot = r * 8 + ((h * 4 + ls) ^ (r & 7));
                ah[mi] = *(const short8*)&LA[0][slot * 8];
            }
            #pragma unroll
            for (int ni = 0; ni < 4; ++ni) {
                int cc = cw + ni * 16 + lm;
                int slot = cc * 8 + ((h * 4 + ls) ^ (cc & 7));
                bh[ni] = *(const short8*)&LA[1][slot * 8];
            }
            #pragma unroll
            for (int ni = 0; ni < 4; ++ni)
                #pragma unroll
                for (int mi = 0; mi < 4; ++mi)
                    acc[mi][ni] = __builtin_amdgcn_mfma_f32_16x16x32_bf16(ah[mi], bh[ni], acc[mi][ni], 0, 0, 0);
        }
    }

    // d2-space epilogue. C/D: row = rw+mi*16+ls*4+v, col = cw+ni*16+lm
    const float INFF = __uint_as_float(INF_BITS);
    float sc[4], mp2c[4];
    int lc[4];
    #pragma unroll
    for (int ni = 0; ni < 4; ++ni) {
        int cl = cw + ni * 16 + lm;
        sc[ni]   = s_sqc[cl];
        mp2c[ni] = s_mp2c[cl];
        lc[ni]   = s_labc[cl];
    }
    float vminc[4];
    #pragma unroll
    for (int ni = 0; ni < 4; ++ni) vminc[ni] = INFF;

    #pragma unroll
    for (int mi = 0; mi < 4; ++mi) {
        #pragma unroll
        for (int v = 0; v < 4; ++v) {
            int rl = rw + mi * 16 + ls * 4 + v;
            float mp2r = s_mp2r[rl];
            float sr   = s_sqr[rl];
            int   li   = s_labr[rl];
            float vminr = INFF;
            #pragma unroll
            for (int ni = 0; ni < 4; ++ni) {
                float d2 = fmaf(-2.0f, acc[mi][ni][v], sr + sc[ni]);
                bool neq = (li != lc[ni]);
                vminr     = fminf(vminr,     (neq && d2 > mp2r)     ? d2 : INFF);
                vminc[ni] = fminf(vminc[ni], (neq && d2 > mp2c[ni]) ? d2 : INFF);
            }
            #pragma unroll
            for (int off = 8; off; off >>= 1)
                vminr = fminf(vminr, __shfl_xor(vminr, off, 64));
            if (lm == 0 && __float_as_uint(vminr) != INF_BITS)
                atomicMin(&minbits[i0 + rl], __float_as_uint(vminr));
        }
    }
    if (!diag) {
        #pragma unroll
        for (int ni = 0; ni < 4; ++ni) {
            float vc = vminc[ni];
            vc = fminf(vc, __shfl_xor(vc, 16, 64));
            vc = fminf(vc, __shfl_xor(vc, 32, 64));
            if (ls == 0 && __float_as_uint(vc) != INF_BITS)
                atomicMin(&minbits[j0 + cw + ni * 16 + lm], __float_as_uint(vc));
        }
    }

    // ---- fused final reduction (fence-free; see header comment) ----
    __shared__ int s_last;
    __syncthreads();   // compiler emits s_waitcnt vmcnt(0) here -> atomics done
    if (tid == 0) s_last = (atomicAdd(done, 1u) == (unsigned)(Tot - 1)) ? 1 : 0;
    __syncthreads();
    if (s_last) {
        float lsum = 0.f; int lcnt = 0;
        for (int i = tid; i < Bn; i += 256) {
            unsigned mb = atomicMin(&minbits[i], INF_BITS);   // coherent read
            int pc = poscnt[i];
            bool valid = (pc > 1) && (pc < Bn);
            if (valid && mb != INF_BITS) {
                float v = fmaf(meanpos[i], pcinv[i],
                               MARGIN - sqrtf(__uint_as_float(mb)));
                lsum += (v > 0.f) ? v : 0.f;
                lcnt += 1;
            }
        }
        __shared__ float ssum[4]; __shared__ int scnt[4];
        #pragma unroll
        for (int off = 32; off; off >>= 1) {
            lsum += __shfl_down(lsum, off, 64);
            lcnt += __shfl_down(lcnt, off, 64);
        }
        if (L == 0) { ssum[w] = lsum; scnt[w] = lcnt; }
        __syncthreads();
        if (tid == 0) {
            float s = ssum[0] + ssum[1] + ssum[2] + ssum[3];
            int   c = scnt[0] + scnt[1] + scnt[2] + scnt[3];
            out[0] = (c > 0) ? s / (float)c : 0.f;
        }
    }
}

// ---------------------------------------------------------------------------
extern "C" void kernel_launch(void* const* d_in, const int* in_sizes, int n_in,
                              void* d_out, int out_size, void* d_ws, size_t ws_size,
                              hipStream_t stream) {
    const float* x = (const float*)d_in[0];
    const int* lab = (const int*)d_in[1];
    int Bn = in_sizes[1];                 // 8192; D fixed at 512

    size_t nd = (size_t)(Bn + PADR) * D;  // padded for banded over-read
    unsigned short* fh = (unsigned short*)d_ws;
    float* sqp        = (float*)(fh + nd);
    float* meanpos    = sqp + Bn;         // raw dist-sums
    float* pcinv      = meanpos + Bn;
    int* poscnt       = (int*)(pcinv + Bn);
    unsigned* minbits = (unsigned*)(poscnt + Bn);
    int* pos          = (int*)(minbits + Bn);
    int* labp         = pos + Bn;
    int* cstart_g     = labp + Bn;
    int* ccnt_g       = cstart_g + NCLS;
    unsigned* done    = (unsigned*)(ccnt_g + NCLS);

    k_bucket<<<1, 1024, 0, stream>>>(lab, Bn, pos, labp, cstart_g, ccnt_g,
                                     meanpos, pcinv, poscnt, minbits, done);
    k_normalize<<<Bn / 4, 256, 0, stream>>>(x, pos, fh, sqp);
    k_posband3<<<Bn / 16, 256, 0, stream>>>(fh, sqp, labp, cstart_g, ccnt_g,
                                            meanpos, Bn);
    int nb = Bn / 128;
    int T = nb * (nb + 1) / 2;            // 2080, divisible by 8
    k_minsh_mfma<<<T, 256, 0, stream>>>(fh, sqp, labp, meanpos, pcinv, poscnt,
                                        minbits, done, (float*)d_out, Bn, T);
}

// Round 10
// 178.526 us; speedup vs baseline: 1.0410x; 1.0410x over previous
//
#include <hip/hip_runtime.h>
#include <math.h>

#define EPS_N 1e-12f
#define MARGIN 0.3f
#define INF_BITS 0x7f800000u
#define NCLS 128     // label space (randint(0,128))
#define D 512
#define PADR 256     // padded rows after fh so banded staging can over-read safely

typedef __attribute__((ext_vector_type(8))) short short8;   // 8 bf16 = 4 VGPRs
typedef __attribute__((ext_vector_type(4))) float float4v;  // MFMA 16x16 accum

__device__ __forceinline__ unsigned short f2bf(float f) {   // RNE bf16
    unsigned u = __float_as_uint(f);
    u += 0x7fff + ((u >> 16) & 1);
    return (unsigned short)(u >> 16);
}
__device__ __forceinline__ void gl16(const void* g, void* l) {
    // 16B async global->LDS; global addr per-lane, LDS dest = uniform base + lane*16
    __builtin_amdgcn_global_load_lds((const __attribute__((address_space(1))) void*)g,
                                     (__attribute__((address_space(3))) void*)l, 16, 0, 0);
}

// ---------------------------------------------------------------------------
// K0: one-block bucketing, coalesced-metadata (kept from R9 — helpers went
// 112 -> 95 us). Phases: LDS histogram -> LDS scan -> coalesced per-slot
// metadata via binary-search class-of-slot -> pos scatter. Zeroes `done`.
// ---------------------------------------------------------------------------
__global__ __launch_bounds__(1024) void k_bucket(const int* __restrict__ lab, int Bn,
        int* __restrict__ pos, int* __restrict__ labp,
        int* __restrict__ cstart_g, int* __restrict__ ccnt_g,
        float* __restrict__ meanpos, float* __restrict__ pcinv,
        int* __restrict__ poscnt, unsigned* __restrict__ minbits,
        unsigned* __restrict__ done) {
    __shared__ int cnt[NCLS], cs[NCLS + 1], off[NCLS], sa[NCLS], sb[NCLS];
    int tid = threadIdx.x;
    if (tid == 0) done[0] = 0u;
    if (tid < NCLS) cnt[tid] = 0;
    __syncthreads();
    for (int i = tid; i < Bn; i += 1024) atomicAdd(&cnt[lab[i] & (NCLS - 1)], 1);
    __syncthreads();
    if (tid < NCLS) sa[tid] = cnt[tid];
    __syncthreads();
    int* src = sa; int* dst = sb;
    for (int ofs = 1; ofs < NCLS; ofs <<= 1) {          // Hillis-Steele inclusive
        if (tid < NCLS) dst[tid] = src[tid] + ((tid >= ofs) ? src[tid - ofs] : 0);
        __syncthreads();
        int* t = src; src = dst; dst = t;
    }
    if (tid < NCLS) {
        int ex = src[tid] - cnt[tid];                   // exclusive
        cs[tid] = ex;
        off[tid] = ex;
        cstart_g[tid] = ex;
        ccnt_g[tid] = cnt[tid];
    }
    if (tid == 0) cs[NCLS] = Bn;
    __syncthreads();
    // coalesced per-slot metadata: class(p) = largest l with cs[l] <= p
    for (int p = tid; p < Bn; p += 1024) {
        int lo = 0, hi = NCLS - 1;
        #pragma unroll
        for (int s = 0; s < 7; ++s) {
            int mid = (lo + hi + 1) >> 1;
            if (cs[mid] <= p) lo = mid; else hi = mid - 1;
        }
        int l = lo, m = cnt[l];
        labp[p] = l;
        poscnt[p] = m;
        pcinv[p] = 1.0f / (float)m;
        meanpos[p] = 0.f;          // accumulates raw dist-sums (posband3)
        minbits[p] = INF_BITS;
    }
    // pos scatter (reads coalesced; only pos[] store is scattered-by-class)
    for (int i = tid; i < Bn; i += 1024) {
        int l = lab[i] & (NCLS - 1);
        pos[i] = atomicAdd(&off[l], 1);
    }
}

// ---------------------------------------------------------------------------
// K1: normalize; one wave per row, no __syncthreads.
// ---------------------------------------------------------------------------
__global__ __launch_bounds__(256) void k_normalize(const float* __restrict__ x,
        const int* __restrict__ pos, unsigned short* __restrict__ fh,
        float* __restrict__ sqp) {
    int w = threadIdx.x >> 6, L = threadIdx.x & 63;
    int row = blockIdx.x * 4 + w;
    const float* xr = x + (size_t)row * D + L * 8;
    float4 a = *(const float4*)xr;
    float4 b = *(const float4*)(xr + 4);
    float ss = a.x * a.x;
    ss = fmaf(a.y, a.y, ss); ss = fmaf(a.z, a.z, ss); ss = fmaf(a.w, a.w, ss);
    ss = fmaf(b.x, b.x, ss); ss = fmaf(b.y, b.y, ss);
    ss = fmaf(b.z, b.z, ss); ss = fmaf(b.w, b.w, ss);
    #pragma unroll
    for (int off = 32; off; off >>= 1) ss += __shfl_xor(ss, off, 64);
    float inv = 1.0f / fmaxf(sqrtf(ss), EPS_N);
    int prow = pos[row];
    if (L == 0) sqp[prow] = ss * inv * inv;
    ushort4 h0, h1;
    h0.x = f2bf(a.x * inv); h0.y = f2bf(a.y * inv);
    h0.z = f2bf(a.z * inv); h0.w = f2bf(a.w * inv);
    h1.x = f2bf(b.x * inv); h1.y = f2bf(b.y * inv);
    h1.z = f2bf(b.z * inv); h1.w = f2bf(b.w * inv);
    unsigned short* dst = fh + (size_t)prow * D + L * 8;
    *(ushort4*)dst = h0;
    *(ushort4*)(dst + 4) = h1;
}

// ---------------------------------------------------------------------------
// K2: banded positive stats v3 (unchanged). One block per 16-row group
// (512 blocks, 2/CU), full class window, BK=128.
// ---------------------------------------------------------------------------
__global__ __launch_bounds__(256) void k_posband3(
    const unsigned short* __restrict__ fh, const float* __restrict__ sqp,
    const int* __restrict__ labp, const int* __restrict__ cstart_g,
    const int* __restrict__ ccnt_g, float* __restrict__ meanpos, int Bn)
{
    __shared__ unsigned short SA[16 * 128];    // 4 KB per K-chunk
    __shared__ unsigned short SB[128 * 128];   // 32 KB per K-chunk
    __shared__ float sqr[16], rs[16];
    __shared__ int labr[16];
    __shared__ float sqc[128];
    __shared__ int labc[128];

    const int r0 = blockIdx.x * 16;
    const int tid = threadIdx.x, w = tid >> 6, L = tid & 63;
    const int lm = L & 15, ls = L >> 4;
    const int srow = L >> 4;      // 0..3 rows per gl16 group
    const int sseg = L & 15;      // 16-B seg slot within a 256 B row

    if (tid < 16) {
        labr[tid] = labp[r0 + tid];
        sqr[tid]  = sqp[r0 + tid];
        rs[tid]   = 0.f;
    }
    __syncthreads();
    const int c0 = cstart_g[labr[0]];
    const int c1 = cstart_g[labr[15]] + ccnt_g[labr[15]];

    for (int cc0 = c0; cc0 < c1; cc0 += 128) {
        __syncthreads();
        if (tid < 128) {
            int q = cc0 + tid;
            if (q < Bn) { sqc[tid] = sqp[q]; labc[tid] = labp[q]; }
            else        { sqc[tid] = 0.f;    labc[tid] = -1; }
        }
        float4v acc[2];
        acc[0] = (float4v){0.f, 0.f, 0.f, 0.f};
        acc[1] = (float4v){0.f, 0.f, 0.f, 0.f};

        for (int k0 = 0; k0 < D; k0 += 128) {
            __syncthreads();
            {   // SA: wave w stages rows w*4 .. w*4+3 (one gl16)
                int rmat = w * 4 + srow;
                int seg = sseg ^ (rmat & 15);
                gl16(fh + (size_t)(r0 + rmat) * D + k0 + seg * 8, &SA[(w * 4) * 128]);
            }
            #pragma unroll
            for (int it = 0; it < 8; ++it) {  // SB: 32 gl16 across 4 waves
                int rmat = it * 16 + w * 4 + srow;          // 0..127 (may over-read pad)
                int seg = sseg ^ (rmat & 15);
                gl16(fh + (size_t)(cc0 + rmat) * D + k0 + seg * 8,
                     &SB[(size_t)(it * 16 + w * 4) * 128]);
            }
            __syncthreads();
            #pragma unroll
            for (int h = 0; h < 4; ++h) {      // K=128 in 4 MFMA sub-steps
                int ra = lm;
                short8 af = *(const short8*)&SA[ra * 128 + (((h * 4 + ls) ^ (ra & 15))) * 8];
                #pragma unroll
                for (int ct = 0; ct < 2; ++ct) {
                    int rb = w * 32 + ct * 16 + lm;
                    short8 bf = *(const short8*)&SB[rb * 128 + (((h * 4 + ls) ^ (rb & 15))) * 8];
                    acc[ct] = __builtin_amdgcn_mfma_f32_16x16x32_bf16(af, bf, acc[ct], 0, 0, 0);
                }
            }
        }
        // epilogue: masked dist row-sums. C/D: row = ls*4+v, col = w*32+ct*16+lm
        #pragma unroll
        for (int v = 0; v < 4; ++v) {
            int ri = ls * 4 + v;
            int p = r0 + ri;
            int lr = labr[ri];
            float sr = sqr[ri];
            float sum = 0.f;
            #pragma unroll
            for (int ct = 0; ct < 2; ++ct) {
                int ci = w * 32 + ct * 16 + lm;
                int q = cc0 + ci;
                float d2 = sr + sqc[ci] - 2.0f * acc[ct][v];
                float dd = (d2 > 0.f) ? sqrtf(d2) : 0.f;
                sum += ((labc[ci] == lr) && (q != p)) ? dd : 0.f;
            }
            #pragma unroll
            for (int off = 8; off; off >>= 1) sum += __shfl_xor(sum, off, 64);
            if (lm == 0) atomicAdd(&rs[ri], sum);
        }
    }
    __syncthreads();
    if (tid < 16 && rs[tid] != 0.f) atomicAdd(&meanpos[r0 + tid], rs[tid]);
}

// ---------------------------------------------------------------------------
// K3: hi-only bf16 MFMA GEMM + fused semi-hard min. R10: NO tile remap
// (R9 post-mortem: contiguous-per-XCD ranges -> cross-XCD load imbalance,
// 1.44x dilation; default round-robin dispatch is the balanced scheme).
// Fence-free fused final reduction kept (proven correct & cheap).
// ---------------------------------------------------------------------------
#define BKG 64

__global__ __launch_bounds__(256, 4) void k_minsh_mfma(
    const unsigned short* __restrict__ fh, const float* __restrict__ sqp,
    const int* __restrict__ labp, const float* __restrict__ meanpos,
    const float* __restrict__ pcinv, const int* __restrict__ poscnt,
    unsigned* __restrict__ minbits, unsigned* __restrict__ done,
    float* __restrict__ out, int Bn, int Tot)
{
    int t = blockIdx.x;
    int rq = (int)((sqrtf(8.0f * (float)t + 1.0f) - 1.0f) * 0.5f);
    while ((rq + 1) * (rq + 2) / 2 <= t) ++rq;
    while (rq * (rq + 1) / 2 > t) --rq;
    int cq = t - rq * (rq + 1) / 2;
    const int i0 = cq * 128, j0 = rq * 128;
    const bool diag = (i0 == j0);

    __shared__ unsigned short LA[2][128 * BKG];   // 32 KB
    __shared__ float s_mp2r[128], s_mp2c[128], s_sqr[128], s_sqc[128];
    __shared__ int s_labr[128], s_labc[128];

    const int tid = threadIdx.x;
    const int w = tid >> 6, L = tid & 63;

    if (tid < 128) {
        float mp = meanpos[i0 + tid] * pcinv[i0 + tid];
        s_mp2r[tid] = mp * mp;
        s_sqr[tid]  = sqp[i0 + tid];
        s_labr[tid] = labp[i0 + tid];
    } else {
        int q = tid - 128;
        float mp = meanpos[j0 + q] * pcinv[j0 + q];
        s_mp2c[q] = mp * mp;
        s_sqc[q]  = sqp[j0 + q];
        s_labc[q] = labp[j0 + q];
    }

    const unsigned short* msrc = fh + (size_t)((w < 2) ? i0 : j0) * D;
    unsigned short* mylds = &LA[(w < 2) ? 0 : 1][(w & 1) * 64 * BKG];
    const int srow = L >> 3;
    const int sseg = L & 7;

    float4v acc[4][4];
    #pragma unroll
    for (int a = 0; a < 4; ++a)
        #pragma unroll
        for (int bq = 0; bq < 4; ++bq) acc[a][bq] = (float4v){0.f, 0.f, 0.f, 0.f};

    const int rw = (w >> 1) * 64, cw = (w & 1) * 64;
    const int lm = L & 15, ls = L >> 4;

    for (int k0 = 0; k0 < D; k0 += BKG) {
        __syncthreads();
        #pragma unroll
        for (int it = 0; it < 8; ++it) {
            int rmat = (w & 1) * 64 + it * 8 + srow;
            int seg = sseg ^ (rmat & 7);
            gl16(msrc + (size_t)rmat * D + k0 + seg * 8, mylds + it * 512);
        }
        __syncthreads();
        #pragma unroll
        for (int h = 0; h < 2; ++h) {
            short8 ah[4], bh[4];
            #pragma unroll
            for (int mi = 0; mi < 4; ++mi) {
                int r = rw + mi * 16 + lm;
                int slot = r * 8 + ((h * 4 + ls) ^ (r & 7));
                ah[mi] = *(const short8*)&LA[0][slot * 8];
            }
            #pragma unroll
            for (int ni = 0; ni < 4; ++ni) {
                int cc = cw + ni * 16 + lm;
                int slot = cc * 8 + ((h * 4 + ls) ^ (cc & 7));
                bh[ni] = *(const short8*)&LA[1][slot * 8];
            }
            #pragma unroll
            for (int ni = 0; ni < 4; ++ni)
                #pragma unroll
                for (int mi = 0; mi < 4; ++mi)
                    acc[mi][ni] = __builtin_amdgcn_mfma_f32_16x16x32_bf16(ah[mi], bh[ni], acc[mi][ni], 0, 0, 0);
        }
    }

    // d2-space epilogue. C/D: row = rw+mi*16+ls*4+v, col = cw+ni*16+lm
    const float INFF = __uint_as_float(INF_BITS);
    float sc[4], mp2c[4];
    int lc[4];
    #pragma unroll
    for (int ni = 0; ni < 4; ++ni) {
        int cl = cw + ni * 16 + lm;
        sc[ni]   = s_sqc[cl];
        mp2c[ni] = s_mp2c[cl];
        lc[ni]   = s_labc[cl];
    }
    float vminc[4];
    #pragma unroll
    for (int ni = 0; ni < 4; ++ni) vminc[ni] = INFF;

    #pragma unroll
    for (int mi = 0; mi < 4; ++mi) {
        #pragma unroll
        for (int v = 0; v < 4; ++v) {
            int rl = rw + mi * 16 + ls * 4 + v;
            float mp2r = s_mp2r[rl];
            float sr   = s_sqr[rl];
            int   li   = s_labr[rl];
            float vminr = INFF;
            #pragma unroll
            for (int ni = 0; ni < 4; ++ni) {
                float d2 = fmaf(-2.0f, acc[mi][ni][v], sr + sc[ni]);
                bool neq = (li != lc[ni]);
                vminr     = fminf(vminr,     (neq && d2 > mp2r)     ? d2 : INFF);
                vminc[ni] = fminf(vminc[ni], (neq && d2 > mp2c[ni]) ? d2 : INFF);
            }
            #pragma unroll
            for (int off = 8; off; off >>= 1)
                vminr = fminf(vminr, __shfl_xor(vminr, off, 64));
            if (lm == 0 && __float_as_uint(vminr) != INF_BITS)
                atomicMin(&minbits[i0 + rl], __float_as_uint(vminr));
        }
    }
    if (!diag) {
        #pragma unroll
        for (int ni = 0; ni < 4; ++ni) {
            float vc = vminc[ni];
            vc = fminf(vc, __shfl_xor(vc, 16, 64));
            vc = fminf(vc, __shfl_xor(vc, 32, 64));
            if (ls == 0 && __float_as_uint(vc) != INF_BITS)
                atomicMin(&minbits[j0 + cw + ni * 16 + lm], __float_as_uint(vc));
        }
    }

    // ---- fused final reduction (fence-free; R6's wbl2 trap avoided) ----
    __shared__ int s_last;
    __syncthreads();   // compiler drains vmcnt(0) here -> epilogue atomics done
    if (tid == 0) s_last = (atomicAdd(done, 1u) == (unsigned)(Tot - 1)) ? 1 : 0;
    __syncthreads();
    if (s_last) {
        float lsum = 0.f; int lcnt = 0;
        for (int i = tid; i < Bn; i += 256) {
            unsigned mb = atomicMin(&minbits[i], INF_BITS);   // coherent read
            int pc = poscnt[i];
            bool valid = (pc > 1) && (pc < Bn);
            if (valid && mb != INF_BITS) {
                float v = fmaf(meanpos[i], pcinv[i],
                               MARGIN - sqrtf(__uint_as_float(mb)));
                lsum += (v > 0.f) ? v : 0.f;
                lcnt += 1;
            }
        }
        __shared__ float ssum[4]; __shared__ int scnt[4];
        #pragma unroll
        for (int off = 32; off; off >>= 1) {
            lsum += __shfl_down(lsum, off, 64);
            lcnt += __shfl_down(lcnt, off, 64);
        }
        if (L == 0) { ssum[w] = lsum; scnt[w] = lcnt; }
        __syncthreads();
        if (tid == 0) {
            float s = ssum[0] + ssum[1] + ssum[2] + ssum[3];
            int   c = scnt[0] + scnt[1] + scnt[2] + scnt[3];
            out[0] = (c > 0) ? s / (float)c : 0.f;
        }
    }
}

// ---------------------------------------------------------------------------
extern "C" void kernel_launch(void* const* d_in, const int* in_sizes, int n_in,
                              void* d_out, int out_size, void* d_ws, size_t ws_size,
                              hipStream_t stream) {
    const float* x = (const float*)d_in[0];
    const int* lab = (const int*)d_in[1];
    int Bn = in_sizes[1];                 // 8192; D fixed at 512

    size_t nd = (size_t)(Bn + PADR) * D;  // padded for banded over-read
    unsigned short* fh = (unsigned short*)d_ws;
    float* sqp        = (float*)(fh + nd);
    float* meanpos    = sqp + Bn;         // raw dist-sums
    float* pcinv      = meanpos + Bn;
    int* poscnt       = (int*)(pcinv + Bn);
    unsigned* minbits = (unsigned*)(poscnt + Bn);
    int* pos          = (int*)(minbits + Bn);
    int* labp         = pos + Bn;
    int* cstart_g     = labp + Bn;
    int* ccnt_g       = cstart_g + NCLS;
    unsigned* done    = (unsigned*)(ccnt_g + NCLS);

    k_bucket<<<1, 1024, 0, stream>>>(lab, Bn, pos, labp, cstart_g, ccnt_g,
                                     meanpos, pcinv, poscnt, minbits, done);
    k_normalize<<<Bn / 4, 256, 0, stream>>>(x, pos, fh, sqp);
    k_posband3<<<Bn / 16, 256, 0, stream>>>(fh, sqp, labp, cstart_g, ccnt_g,
                                            meanpos, Bn);
    int nb = Bn / 128;
    int T = nb * (nb + 1) / 2;            // 2080
    k_minsh_mfma<<<T, 256, 0, stream>>>(fh, sqp, labp, meanpos, pcinv, poscnt,
                                        minbits, done, (float*)d_out, Bn, T);
}

// Round 11
// 170.412 us; speedup vs baseline: 1.0906x; 1.0476x over previous
//
#include <hip/hip_runtime.h>
#include <math.h>

#define EPS_N 1e-12f
#define MARGIN 0.3f
#define INF_BITS 0x7f800000u
#define NCLS 128     // label space (randint(0,128))
#define D 512
#define PADR 256     // padded rows after fh so banded staging can over-read safely

typedef __attribute__((ext_vector_type(8))) short short8;   // 8 bf16 = 4 VGPRs
typedef __attribute__((ext_vector_type(4))) float float4v;  // MFMA 16x16 accum

__device__ __forceinline__ unsigned short f2bf(float f) {   // RNE bf16
    unsigned u = __float_as_uint(f);
    u += 0x7fff + ((u >> 16) & 1);
    return (unsigned short)(u >> 16);
}
__device__ __forceinline__ void gl16(const void* g, void* l) {
    // 16B async global->LDS; global addr per-lane, LDS dest = uniform base + lane*16
    __builtin_amdgcn_global_load_lds((const __attribute__((address_space(1))) void*)g,
                                     (__attribute__((address_space(3))) void*)l, 16, 0, 0);
}

// ---------------------------------------------------------------------------
// K0: one-block bucketing, coalesced-metadata (unchanged from R10).
// ---------------------------------------------------------------------------
__global__ __launch_bounds__(1024) void k_bucket(const int* __restrict__ lab, int Bn,
        int* __restrict__ pos, int* __restrict__ labp,
        int* __restrict__ cstart_g, int* __restrict__ ccnt_g,
        float* __restrict__ meanpos, float* __restrict__ pcinv,
        int* __restrict__ poscnt, unsigned* __restrict__ minbits,
        unsigned* __restrict__ done) {
    __shared__ int cnt[NCLS], cs[NCLS + 1], off[NCLS], sa[NCLS], sb[NCLS];
    int tid = threadIdx.x;
    if (tid == 0) done[0] = 0u;
    if (tid < NCLS) cnt[tid] = 0;
    __syncthreads();
    for (int i = tid; i < Bn; i += 1024) atomicAdd(&cnt[lab[i] & (NCLS - 1)], 1);
    __syncthreads();
    if (tid < NCLS) sa[tid] = cnt[tid];
    __syncthreads();
    int* src = sa; int* dst = sb;
    for (int ofs = 1; ofs < NCLS; ofs <<= 1) {          // Hillis-Steele inclusive
        if (tid < NCLS) dst[tid] = src[tid] + ((tid >= ofs) ? src[tid - ofs] : 0);
        __syncthreads();
        int* t = src; src = dst; dst = t;
    }
    if (tid < NCLS) {
        int ex = src[tid] - cnt[tid];                   // exclusive
        cs[tid] = ex;
        off[tid] = ex;
        cstart_g[tid] = ex;
        ccnt_g[tid] = cnt[tid];
    }
    if (tid == 0) cs[NCLS] = Bn;
    __syncthreads();
    // coalesced per-slot metadata: class(p) = largest l with cs[l] <= p
    for (int p = tid; p < Bn; p += 1024) {
        int lo = 0, hi = NCLS - 1;
        #pragma unroll
        for (int s = 0; s < 7; ++s) {
            int mid = (lo + hi + 1) >> 1;
            if (cs[mid] <= p) lo = mid; else hi = mid - 1;
        }
        int l = lo, m = cnt[l];
        labp[p] = l;
        poscnt[p] = m;
        pcinv[p] = 1.0f / (float)m;
        meanpos[p] = 0.f;          // accumulates raw dist-sums (posband3)
        minbits[p] = INF_BITS;
    }
    // pos scatter (reads coalesced; only pos[] store is scattered-by-class)
    for (int i = tid; i < Bn; i += 1024) {
        int l = lab[i] & (NCLS - 1);
        pos[i] = atomicAdd(&off[l], 1);
    }
}

// ---------------------------------------------------------------------------
// K1: normalize; one wave per row, no __syncthreads (unchanged).
// ---------------------------------------------------------------------------
__global__ __launch_bounds__(256) void k_normalize(const float* __restrict__ x,
        const int* __restrict__ pos, unsigned short* __restrict__ fh,
        float* __restrict__ sqp) {
    int w = threadIdx.x >> 6, L = threadIdx.x & 63;
    int row = blockIdx.x * 4 + w;
    const float* xr = x + (size_t)row * D + L * 8;
    float4 a = *(const float4*)xr;
    float4 b = *(const float4*)(xr + 4);
    float ss = a.x * a.x;
    ss = fmaf(a.y, a.y, ss); ss = fmaf(a.z, a.z, ss); ss = fmaf(a.w, a.w, ss);
    ss = fmaf(b.x, b.x, ss); ss = fmaf(b.y, b.y, ss);
    ss = fmaf(b.z, b.z, ss); ss = fmaf(b.w, b.w, ss);
    #pragma unroll
    for (int off = 32; off; off >>= 1) ss += __shfl_xor(ss, off, 64);
    float inv = 1.0f / fmaxf(sqrtf(ss), EPS_N);
    int prow = pos[row];
    if (L == 0) sqp[prow] = ss * inv * inv;
    ushort4 h0, h1;
    h0.x = f2bf(a.x * inv); h0.y = f2bf(a.y * inv);
    h0.z = f2bf(a.z * inv); h0.w = f2bf(a.w * inv);
    h1.x = f2bf(b.x * inv); h1.y = f2bf(b.y * inv);
    h1.z = f2bf(b.z * inv); h1.w = f2bf(b.w * inv);
    unsigned short* dst = fh + (size_t)prow * D + L * 8;
    *(ushort4*)dst = h0;
    *(ushort4*)(dst + 4) = h1;
}

// ---------------------------------------------------------------------------
// K2: banded positive stats v3 (unchanged).
// ---------------------------------------------------------------------------
__global__ __launch_bounds__(256) void k_posband3(
    const unsigned short* __restrict__ fh, const float* __restrict__ sqp,
    const int* __restrict__ labp, const int* __restrict__ cstart_g,
    const int* __restrict__ ccnt_g, float* __restrict__ meanpos, int Bn)
{
    __shared__ unsigned short SA[16 * 128];    // 4 KB per K-chunk
    __shared__ unsigned short SB[128 * 128];   // 32 KB per K-chunk
    __shared__ float sqr[16], rs[16];
    __shared__ int labr[16];
    __shared__ float sqc[128];
    __shared__ int labc[128];

    const int r0 = blockIdx.x * 16;
    const int tid = threadIdx.x, w = tid >> 6, L = tid & 63;
    const int lm = L & 15, ls = L >> 4;
    const int srow = L >> 4;      // 0..3 rows per gl16 group
    const int sseg = L & 15;      // 16-B seg slot within a 256 B row

    if (tid < 16) {
        labr[tid] = labp[r0 + tid];
        sqr[tid]  = sqp[r0 + tid];
        rs[tid]   = 0.f;
    }
    __syncthreads();
    const int c0 = cstart_g[labr[0]];
    const int c1 = cstart_g[labr[15]] + ccnt_g[labr[15]];

    for (int cc0 = c0; cc0 < c1; cc0 += 128) {
        __syncthreads();
        if (tid < 128) {
            int q = cc0 + tid;
            if (q < Bn) { sqc[tid] = sqp[q]; labc[tid] = labp[q]; }
            else        { sqc[tid] = 0.f;    labc[tid] = -1; }
        }
        float4v acc[2];
        acc[0] = (float4v){0.f, 0.f, 0.f, 0.f};
        acc[1] = (float4v){0.f, 0.f, 0.f, 0.f};

        for (int k0 = 0; k0 < D; k0 += 128) {
            __syncthreads();
            {   // SA: wave w stages rows w*4 .. w*4+3 (one gl16)
                int rmat = w * 4 + srow;
                int seg = sseg ^ (rmat & 15);
                gl16(fh + (size_t)(r0 + rmat) * D + k0 + seg * 8, &SA[(w * 4) * 128]);
            }
            #pragma unroll
            for (int it = 0; it < 8; ++it) {  // SB: 32 gl16 across 4 waves
                int rmat = it * 16 + w * 4 + srow;          // 0..127 (may over-read pad)
                int seg = sseg ^ (rmat & 15);
                gl16(fh + (size_t)(cc0 + rmat) * D + k0 + seg * 8,
                     &SB[(size_t)(it * 16 + w * 4) * 128]);
            }
            __syncthreads();
            #pragma unroll
            for (int h = 0; h < 4; ++h) {      // K=128 in 4 MFMA sub-steps
                int ra = lm;
                short8 af = *(const short8*)&SA[ra * 128 + (((h * 4 + ls) ^ (ra & 15))) * 8];
                #pragma unroll
                for (int ct = 0; ct < 2; ++ct) {
                    int rb = w * 32 + ct * 16 + lm;
                    short8 bf = *(const short8*)&SB[rb * 128 + (((h * 4 + ls) ^ (rb & 15))) * 8];
                    acc[ct] = __builtin_amdgcn_mfma_f32_16x16x32_bf16(af, bf, acc[ct], 0, 0, 0);
                }
            }
        }
        // epilogue: masked dist row-sums. C/D: row = ls*4+v, col = w*32+ct*16+lm
        #pragma unroll
        for (int v = 0; v < 4; ++v) {
            int ri = ls * 4 + v;
            int p = r0 + ri;
            int lr = labr[ri];
            float sr = sqr[ri];
            float sum = 0.f;
            #pragma unroll
            for (int ct = 0; ct < 2; ++ct) {
                int ci = w * 32 + ct * 16 + lm;
                int q = cc0 + ci;
                float d2 = sr + sqc[ci] - 2.0f * acc[ct][v];
                float dd = (d2 > 0.f) ? sqrtf(d2) : 0.f;
                sum += ((labc[ci] == lr) && (q != p)) ? dd : 0.f;
            }
            #pragma unroll
            for (int off = 8; off; off >>= 1) sum += __shfl_xor(sum, off, 64);
            if (lm == 0) atomicAdd(&rs[ri], sum);
        }
    }
    __syncthreads();
    if (tid < 16 && rs[tid] != 0.f) atomicAdd(&meanpos[r0 + tid], rs[tid]);
}

// ---------------------------------------------------------------------------
// K3: hi-only bf16 MFMA GEMM + fused semi-hard min. R11: tail's coherent
// atomicMin reads BATCHED 8-wide so latency pipelines (R10 post-mortem: the
// per-iteration consume serialized 32 x ~1200cyc atomic round-trips in one
// block = ~25 us of idle straggle; batching -> ~2.5 us).
// ---------------------------------------------------------------------------
#define BKG 64

__global__ __launch_bounds__(256, 4) void k_minsh_mfma(
    const unsigned short* __restrict__ fh, const float* __restrict__ sqp,
    const int* __restrict__ labp, const float* __restrict__ meanpos,
    const float* __restrict__ pcinv, const int* __restrict__ poscnt,
    unsigned* __restrict__ minbits, unsigned* __restrict__ done,
    float* __restrict__ out, int Bn, int Tot)
{
    int t = blockIdx.x;
    int rq = (int)((sqrtf(8.0f * (float)t + 1.0f) - 1.0f) * 0.5f);
    while ((rq + 1) * (rq + 2) / 2 <= t) ++rq;
    while (rq * (rq + 1) / 2 > t) --rq;
    int cq = t - rq * (rq + 1) / 2;
    const int i0 = cq * 128, j0 = rq * 128;
    const bool diag = (i0 == j0);

    __shared__ unsigned short LA[2][128 * BKG];   // 32 KB
    __shared__ float s_mp2r[128], s_mp2c[128], s_sqr[128], s_sqc[128];
    __shared__ int s_labr[128], s_labc[128];

    const int tid = threadIdx.x;
    const int w = tid >> 6, L = tid & 63;

    if (tid < 128) {
        float mp = meanpos[i0 + tid] * pcinv[i0 + tid];
        s_mp2r[tid] = mp * mp;
        s_sqr[tid]  = sqp[i0 + tid];
        s_labr[tid] = labp[i0 + tid];
    } else {
        int q = tid - 128;
        float mp = meanpos[j0 + q] * pcinv[j0 + q];
        s_mp2c[q] = mp * mp;
        s_sqc[q]  = sqp[j0 + q];
        s_labc[q] = labp[j0 + q];
    }

    const unsigned short* msrc = fh + (size_t)((w < 2) ? i0 : j0) * D;
    unsigned short* mylds = &LA[(w < 2) ? 0 : 1][(w & 1) * 64 * BKG];
    const int srow = L >> 3;
    const int sseg = L & 7;

    float4v acc[4][4];
    #pragma unroll
    for (int a = 0; a < 4; ++a)
        #pragma unroll
        for (int bq = 0; bq < 4; ++bq) acc[a][bq] = (float4v){0.f, 0.f, 0.f, 0.f};

    const int rw = (w >> 1) * 64, cw = (w & 1) * 64;
    const int lm = L & 15, ls = L >> 4;

    for (int k0 = 0; k0 < D; k0 += BKG) {
        __syncthreads();
        #pragma unroll
        for (int it = 0; it < 8; ++it) {
            int rmat = (w & 1) * 64 + it * 8 + srow;
            int seg = sseg ^ (rmat & 7);
            gl16(msrc + (size_t)rmat * D + k0 + seg * 8, mylds + it * 512);
        }
        __syncthreads();
        #pragma unroll
        for (int h = 0; h < 2; ++h) {
            short8 ah[4], bh[4];
            #pragma unroll
            for (int mi = 0; mi < 4; ++mi) {
                int r = rw + mi * 16 + lm;
                int slot = r * 8 + ((h * 4 + ls) ^ (r & 7));
                ah[mi] = *(const short8*)&LA[0][slot * 8];
            }
            #pragma unroll
            for (int ni = 0; ni < 4; ++ni) {
                int cc = cw + ni * 16 + lm;
                int slot = cc * 8 + ((h * 4 + ls) ^ (cc & 7));
                bh[ni] = *(const short8*)&LA[1][slot * 8];
            }
            #pragma unroll
            for (int ni = 0; ni < 4; ++ni)
                #pragma unroll
                for (int mi = 0; mi < 4; ++mi)
                    acc[mi][ni] = __builtin_amdgcn_mfma_f32_16x16x32_bf16(ah[mi], bh[ni], acc[mi][ni], 0, 0, 0);
        }
    }

    // d2-space epilogue. C/D: row = rw+mi*16+ls*4+v, col = cw+ni*16+lm
    const float INFF = __uint_as_float(INF_BITS);
    float sc[4], mp2c[4];
    int lc[4];
    #pragma unroll
    for (int ni = 0; ni < 4; ++ni) {
        int cl = cw + ni * 16 + lm;
        sc[ni]   = s_sqc[cl];
        mp2c[ni] = s_mp2c[cl];
        lc[ni]   = s_labc[cl];
    }
    float vminc[4];
    #pragma unroll
    for (int ni = 0; ni < 4; ++ni) vminc[ni] = INFF;

    #pragma unroll
    for (int mi = 0; mi < 4; ++mi) {
        #pragma unroll
        for (int v = 0; v < 4; ++v) {
            int rl = rw + mi * 16 + ls * 4 + v;
            float mp2r = s_mp2r[rl];
            float sr   = s_sqr[rl];
            int   li   = s_labr[rl];
            float vminr = INFF;
            #pragma unroll
            for (int ni = 0; ni < 4; ++ni) {
                float d2 = fmaf(-2.0f, acc[mi][ni][v], sr + sc[ni]);
                bool neq = (li != lc[ni]);
                vminr     = fminf(vminr,     (neq && d2 > mp2r)     ? d2 : INFF);
                vminc[ni] = fminf(vminc[ni], (neq && d2 > mp2c[ni]) ? d2 : INFF);
            }
            #pragma unroll
            for (int off = 8; off; off >>= 1)
                vminr = fminf(vminr, __shfl_xor(vminr, off, 64));
            if (lm == 0 && __float_as_uint(vminr) != INF_BITS)
                atomicMin(&minbits[i0 + rl], __float_as_uint(vminr));
        }
    }
    if (!diag) {
        #pragma unroll
        for (int ni = 0; ni < 4; ++ni) {
            float vc = vminc[ni];
            vc = fminf(vc, __shfl_xor(vc, 16, 64));
            vc = fminf(vc, __shfl_xor(vc, 32, 64));
            if (ls == 0 && __float_as_uint(vc) != INF_BITS)
                atomicMin(&minbits[j0 + cw + ni * 16 + lm], __float_as_uint(vc));
        }
    }

    // ---- fused final reduction (fence-free, batched atomics) ----
    __shared__ int s_last;
    __syncthreads();   // compiler drains vmcnt(0) here -> epilogue atomics done
    if (tid == 0) s_last = (atomicAdd(done, 1u) == (unsigned)(Tot - 1)) ? 1 : 0;
    __syncthreads();
    if (s_last) {
        float lsum = 0.f; int lcnt = 0;
        for (int b0 = 0; b0 < Bn; b0 += 256 * 8) {
            unsigned mb[8]; int pc[8]; float mpv[8], pci[8];
            #pragma unroll
            for (int u = 0; u < 8; ++u) {           // issue 8 independent atomics
                int i = b0 + u * 256 + tid;
                bool ok = (i < Bn);
                mb[u]  = ok ? atomicMin(&minbits[i], INF_BITS) : INF_BITS;
                pc[u]  = ok ? poscnt[i] : 0;
                mpv[u] = ok ? meanpos[i] : 0.f;
                pci[u] = ok ? pcinv[i] : 0.f;
            }
            #pragma unroll
            for (int u = 0; u < 8; ++u) {           // then consume
                bool valid = (pc[u] > 1) && (pc[u] < Bn);
                if (valid && mb[u] != INF_BITS) {
                    float v = fmaf(mpv[u], pci[u],
                                   MARGIN - sqrtf(__uint_as_float(mb[u])));
                    lsum += (v > 0.f) ? v : 0.f;
                    lcnt += 1;
                }
            }
        }
        __shared__ float ssum[4]; __shared__ int scnt[4];
        #pragma unroll
        for (int off = 32; off; off >>= 1) {
            lsum += __shfl_down(lsum, off, 64);
            lcnt += __shfl_down(lcnt, off, 64);
        }
        if (L == 0) { ssum[w] = lsum; scnt[w] = lcnt; }
        __syncthreads();
        if (tid == 0) {
            float s = ssum[0] + ssum[1] + ssum[2] + ssum[3];
            int   c = scnt[0] + scnt[1] + scnt[2] + scnt[3];
            out[0] = (c > 0) ? s / (float)c : 0.f;
        }
    }
}

// ---------------------------------------------------------------------------
extern "C" void kernel_launch(void* const* d_in, const int* in_sizes, int n_in,
                              void* d_out, int out_size, void* d_ws, size_t ws_size,
                              hipStream_t stream) {
    const float* x = (const float*)d_in[0];
    const int* lab = (const int*)d_in[1];
    int Bn = in_sizes[1];                 // 8192; D fixed at 512

    size_t nd = (size_t)(Bn + PADR) * D;  // padded for banded over-read
    unsigned short* fh = (unsigned short*)d_ws;
    float* sqp        = (float*)(fh + nd);
    float* meanpos    = sqp + Bn;         // raw dist-sums
    float* pcinv      = meanpos + Bn;
    int* poscnt       = (int*)(pcinv + Bn);
    unsigned* minbits = (unsigned*)(poscnt + Bn);
    int* pos          = (int*)(minbits + Bn);
    int* labp         = pos + Bn;
    int* cstart_g     = labp + Bn;
    int* ccnt_g       = cstart_g + NCLS;
    unsigned* done    = (unsigned*)(ccnt_g + NCLS);

    k_bucket<<<1, 1024, 0, stream>>>(lab, Bn, pos, labp, cstart_g, ccnt_g,
                                     meanpos, pcinv, poscnt, minbits, done);
    k_normalize<<<Bn / 4, 256, 0, stream>>>(x, pos, fh, sqp);
    k_posband3<<<Bn / 16, 256, 0, stream>>>(fh, sqp, labp, cstart_g, ccnt_g,
                                            meanpos, Bn);
    int nb = Bn / 128;
    int T = nb * (nb + 1) / 2;            // 2080
    k_minsh_mfma<<<T, 256, 0, stream>>>(fh, sqp, labp, meanpos, pcinv, poscnt,
                                        minbits, done, (float*)d_out, Bn, T);
}

// Round 12
// 162.585 us; speedup vs baseline: 1.1431x; 1.0481x over previous
//
#include <hip/hip_runtime.h>
#include <math.h>

#define EPS_N 1e-12f
#define MARGIN 0.3f
#define INF_BITS 0x7f800000u
#define NCLS 128     // label space (randint(0,128))
#define D 512
#define PADR 256     // padded rows after fh so banded staging can over-read safely

typedef __attribute__((ext_vector_type(8))) short short8;   // 8 bf16 = 4 VGPRs
typedef __attribute__((ext_vector_type(4))) float float4v;  // MFMA 16x16 accum

__device__ __forceinline__ unsigned short f2bf(float f) {   // RNE bf16
    unsigned u = __float_as_uint(f);
    u += 0x7fff + ((u >> 16) & 1);
    return (unsigned short)(u >> 16);
}
__device__ __forceinline__ void gl16(const void* g, void* l) {
    // 16B async global->LDS; global addr per-lane, LDS dest = uniform base + lane*16
    __builtin_amdgcn_global_load_lds((const __attribute__((address_space(1))) void*)g,
                                     (__attribute__((address_space(3))) void*)l, 16, 0, 0);
}

// ---------------------------------------------------------------------------
// K0: one-block bucketing, coalesced-metadata (unchanged from R10/R11).
// ---------------------------------------------------------------------------
__global__ __launch_bounds__(1024) void k_bucket(const int* __restrict__ lab, int Bn,
        int* __restrict__ pos, int* __restrict__ labp,
        int* __restrict__ cstart_g, int* __restrict__ ccnt_g,
        float* __restrict__ meanpos, float* __restrict__ pcinv,
        int* __restrict__ poscnt, unsigned* __restrict__ minbits) {
    __shared__ int cnt[NCLS], cs[NCLS + 1], off[NCLS], sa[NCLS], sb[NCLS];
    int tid = threadIdx.x;
    if (tid < NCLS) cnt[tid] = 0;
    __syncthreads();
    for (int i = tid; i < Bn; i += 1024) atomicAdd(&cnt[lab[i] & (NCLS - 1)], 1);
    __syncthreads();
    if (tid < NCLS) sa[tid] = cnt[tid];
    __syncthreads();
    int* src = sa; int* dst = sb;
    for (int ofs = 1; ofs < NCLS; ofs <<= 1) {          // Hillis-Steele inclusive
        if (tid < NCLS) dst[tid] = src[tid] + ((tid >= ofs) ? src[tid - ofs] : 0);
        __syncthreads();
        int* t = src; src = dst; dst = t;
    }
    if (tid < NCLS) {
        int ex = src[tid] - cnt[tid];                   // exclusive
        cs[tid] = ex;
        off[tid] = ex;
        cstart_g[tid] = ex;
        ccnt_g[tid] = cnt[tid];
    }
    if (tid == 0) cs[NCLS] = Bn;
    __syncthreads();
    // coalesced per-slot metadata: class(p) = largest l with cs[l] <= p
    for (int p = tid; p < Bn; p += 1024) {
        int lo = 0, hi = NCLS - 1;
        #pragma unroll
        for (int s = 0; s < 7; ++s) {
            int mid = (lo + hi + 1) >> 1;
            if (cs[mid] <= p) lo = mid; else hi = mid - 1;
        }
        int l = lo, m = cnt[l];
        labp[p] = l;
        poscnt[p] = m;
        pcinv[p] = 1.0f / (float)m;
        meanpos[p] = 0.f;          // accumulates raw dist-sums (posband3)
        minbits[p] = INF_BITS;
    }
    // pos scatter (reads coalesced; only pos[] store is scattered-by-class)
    for (int i = tid; i < Bn; i += 1024) {
        int l = lab[i] & (NCLS - 1);
        pos[i] = atomicAdd(&off[l], 1);
    }
}

// ---------------------------------------------------------------------------
// K1: normalize; one wave per row, no __syncthreads (unchanged).
// ---------------------------------------------------------------------------
__global__ __launch_bounds__(256) void k_normalize(const float* __restrict__ x,
        const int* __restrict__ pos, unsigned short* __restrict__ fh,
        float* __restrict__ sqp) {
    int w = threadIdx.x >> 6, L = threadIdx.x & 63;
    int row = blockIdx.x * 4 + w;
    const float* xr = x + (size_t)row * D + L * 8;
    float4 a = *(const float4*)xr;
    float4 b = *(const float4*)(xr + 4);
    float ss = a.x * a.x;
    ss = fmaf(a.y, a.y, ss); ss = fmaf(a.z, a.z, ss); ss = fmaf(a.w, a.w, ss);
    ss = fmaf(b.x, b.x, ss); ss = fmaf(b.y, b.y, ss);
    ss = fmaf(b.z, b.z, ss); ss = fmaf(b.w, b.w, ss);
    #pragma unroll
    for (int off = 32; off; off >>= 1) ss += __shfl_xor(ss, off, 64);
    float inv = 1.0f / fmaxf(sqrtf(ss), EPS_N);
    int prow = pos[row];
    if (L == 0) sqp[prow] = ss * inv * inv;
    ushort4 h0, h1;
    h0.x = f2bf(a.x * inv); h0.y = f2bf(a.y * inv);
    h0.z = f2bf(a.z * inv); h0.w = f2bf(a.w * inv);
    h1.x = f2bf(b.x * inv); h1.y = f2bf(b.y * inv);
    h1.z = f2bf(b.z * inv); h1.w = f2bf(b.w * inv);
    unsigned short* dst = fh + (size_t)prow * D + L * 8;
    *(ushort4*)dst = h0;
    *(ushort4*)(dst + 4) = h1;
}

// ---------------------------------------------------------------------------
// K2: banded positive stats v3 (unchanged).
// ---------------------------------------------------------------------------
__global__ __launch_bounds__(256) void k_posband3(
    const unsigned short* __restrict__ fh, const float* __restrict__ sqp,
    const int* __restrict__ labp, const int* __restrict__ cstart_g,
    const int* __restrict__ ccnt_g, float* __restrict__ meanpos, int Bn)
{
    __shared__ unsigned short SA[16 * 128];    // 4 KB per K-chunk
    __shared__ unsigned short SB[128 * 128];   // 32 KB per K-chunk
    __shared__ float sqr[16], rs[16];
    __shared__ int labr[16];
    __shared__ float sqc[128];
    __shared__ int labc[128];

    const int r0 = blockIdx.x * 16;
    const int tid = threadIdx.x, w = tid >> 6, L = tid & 63;
    const int lm = L & 15, ls = L >> 4;
    const int srow = L >> 4;      // 0..3 rows per gl16 group
    const int sseg = L & 15;      // 16-B seg slot within a 256 B row

    if (tid < 16) {
        labr[tid] = labp[r0 + tid];
        sqr[tid]  = sqp[r0 + tid];
        rs[tid]   = 0.f;
    }
    __syncthreads();
    const int c0 = cstart_g[labr[0]];
    const int c1 = cstart_g[labr[15]] + ccnt_g[labr[15]];

    for (int cc0 = c0; cc0 < c1; cc0 += 128) {
        __syncthreads();
        if (tid < 128) {
            int q = cc0 + tid;
            if (q < Bn) { sqc[tid] = sqp[q]; labc[tid] = labp[q]; }
            else        { sqc[tid] = 0.f;    labc[tid] = -1; }
        }
        float4v acc[2];
        acc[0] = (float4v){0.f, 0.f, 0.f, 0.f};
        acc[1] = (float4v){0.f, 0.f, 0.f, 0.f};

        for (int k0 = 0; k0 < D; k0 += 128) {
            __syncthreads();
            {   // SA: wave w stages rows w*4 .. w*4+3 (one gl16)
                int rmat = w * 4 + srow;
                int seg = sseg ^ (rmat & 15);
                gl16(fh + (size_t)(r0 + rmat) * D + k0 + seg * 8, &SA[(w * 4) * 128]);
            }
            #pragma unroll
            for (int it = 0; it < 8; ++it) {  // SB: 32 gl16 across 4 waves
                int rmat = it * 16 + w * 4 + srow;          // 0..127 (may over-read pad)
                int seg = sseg ^ (rmat & 15);
                gl16(fh + (size_t)(cc0 + rmat) * D + k0 + seg * 8,
                     &SB[(size_t)(it * 16 + w * 4) * 128]);
            }
            __syncthreads();
            #pragma unroll
            for (int h = 0; h < 4; ++h) {      // K=128 in 4 MFMA sub-steps
                int ra = lm;
                short8 af = *(const short8*)&SA[ra * 128 + (((h * 4 + ls) ^ (ra & 15))) * 8];
                #pragma unroll
                for (int ct = 0; ct < 2; ++ct) {
                    int rb = w * 32 + ct * 16 + lm;
                    short8 bf = *(const short8*)&SB[rb * 128 + (((h * 4 + ls) ^ (rb & 15))) * 8];
                    acc[ct] = __builtin_amdgcn_mfma_f32_16x16x32_bf16(af, bf, acc[ct], 0, 0, 0);
                }
            }
        }
        // epilogue: masked dist row-sums. C/D: row = ls*4+v, col = w*32+ct*16+lm
        #pragma unroll
        for (int v = 0; v < 4; ++v) {
            int ri = ls * 4 + v;
            int p = r0 + ri;
            int lr = labr[ri];
            float sr = sqr[ri];
            float sum = 0.f;
            #pragma unroll
            for (int ct = 0; ct < 2; ++ct) {
                int ci = w * 32 + ct * 16 + lm;
                int q = cc0 + ci;
                float d2 = sr + sqc[ci] - 2.0f * acc[ct][v];
                float dd = (d2 > 0.f) ? sqrtf(d2) : 0.f;
                sum += ((labc[ci] == lr) && (q != p)) ? dd : 0.f;
            }
            #pragma unroll
            for (int off = 8; off; off >>= 1) sum += __shfl_xor(sum, off, 64);
            if (lm == 0) atomicAdd(&rs[ri], sum);
        }
    }
    __syncthreads();
    if (tid < 16 && rs[tid] != 0.f) atomicAdd(&meanpos[r0 + tid], rs[tid]);
}

// ---------------------------------------------------------------------------
// K3: hi-only bf16 MFMA GEMM + fused semi-hard min — R8 form: NO tail, NO
// done counter (R9-R11 post-mortem: per-block completion signaling costs
// ~1.5-2 us x 8 block-waves/CU = +18 us; a separate finish node is cheaper).
// ---------------------------------------------------------------------------
#define BKG 64

__global__ __launch_bounds__(256, 4) void k_minsh_mfma(
    const unsigned short* __restrict__ fh, const float* __restrict__ sqp,
    const int* __restrict__ labp, const float* __restrict__ meanpos,
    const float* __restrict__ pcinv, unsigned* __restrict__ minbits)
{
    int t = blockIdx.x;
    int rq = (int)((sqrtf(8.0f * (float)t + 1.0f) - 1.0f) * 0.5f);
    while ((rq + 1) * (rq + 2) / 2 <= t) ++rq;
    while (rq * (rq + 1) / 2 > t) --rq;
    int cq = t - rq * (rq + 1) / 2;
    const int i0 = cq * 128, j0 = rq * 128;
    const bool diag = (i0 == j0);

    __shared__ unsigned short LA[2][128 * BKG];   // 32 KB
    __shared__ float s_mp2r[128], s_mp2c[128], s_sqr[128], s_sqc[128];
    __shared__ int s_labr[128], s_labc[128];

    const int tid = threadIdx.x;
    const int w = tid >> 6, L = tid & 63;

    if (tid < 128) {
        float mp = meanpos[i0 + tid] * pcinv[i0 + tid];
        s_mp2r[tid] = mp * mp;
        s_sqr[tid]  = sqp[i0 + tid];
        s_labr[tid] = labp[i0 + tid];
    } else {
        int q = tid - 128;
        float mp = meanpos[j0 + q] * pcinv[j0 + q];
        s_mp2c[q] = mp * mp;
        s_sqc[q]  = sqp[j0 + q];
        s_labc[q] = labp[j0 + q];
    }

    const unsigned short* msrc = fh + (size_t)((w < 2) ? i0 : j0) * D;
    unsigned short* mylds = &LA[(w < 2) ? 0 : 1][(w & 1) * 64 * BKG];
    const int srow = L >> 3;
    const int sseg = L & 7;

    float4v acc[4][4];
    #pragma unroll
    for (int a = 0; a < 4; ++a)
        #pragma unroll
        for (int bq = 0; bq < 4; ++bq) acc[a][bq] = (float4v){0.f, 0.f, 0.f, 0.f};

    const int rw = (w >> 1) * 64, cw = (w & 1) * 64;
    const int lm = L & 15, ls = L >> 4;

    for (int k0 = 0; k0 < D; k0 += BKG) {
        __syncthreads();
        #pragma unroll
        for (int it = 0; it < 8; ++it) {
            int rmat = (w & 1) * 64 + it * 8 + srow;
            int seg = sseg ^ (rmat & 7);
            gl16(msrc + (size_t)rmat * D + k0 + seg * 8, mylds + it * 512);
        }
        __syncthreads();
        #pragma unroll
        for (int h = 0; h < 2; ++h) {
            short8 ah[4], bh[4];
            #pragma unroll
            for (int mi = 0; mi < 4; ++mi) {
                int r = rw + mi * 16 + lm;
                int slot = r * 8 + ((h * 4 + ls) ^ (r & 7));
                ah[mi] = *(const short8*)&LA[0][slot * 8];
            }
            #pragma unroll
            for (int ni = 0; ni < 4; ++ni) {
                int cc = cw + ni * 16 + lm;
                int slot = cc * 8 + ((h * 4 + ls) ^ (cc & 7));
                bh[ni] = *(const short8*)&LA[1][slot * 8];
            }
            #pragma unroll
            for (int ni = 0; ni < 4; ++ni)
                #pragma unroll
                for (int mi = 0; mi < 4; ++mi)
                    acc[mi][ni] = __builtin_amdgcn_mfma_f32_16x16x32_bf16(ah[mi], bh[ni], acc[mi][ni], 0, 0, 0);
        }
    }

    // d2-space epilogue. C/D: row = rw+mi*16+ls*4+v, col = cw+ni*16+lm
    const float INFF = __uint_as_float(INF_BITS);
    float sc[4], mp2c[4];
    int lc[4];
    #pragma unroll
    for (int ni = 0; ni < 4; ++ni) {
        int cl = cw + ni * 16 + lm;
        sc[ni]   = s_sqc[cl];
        mp2c[ni] = s_mp2c[cl];
        lc[ni]   = s_labc[cl];
    }
    float vminc[4];
    #pragma unroll
    for (int ni = 0; ni < 4; ++ni) vminc[ni] = INFF;

    #pragma unroll
    for (int mi = 0; mi < 4; ++mi) {
        #pragma unroll
        for (int v = 0; v < 4; ++v) {
            int rl = rw + mi * 16 + ls * 4 + v;
            float mp2r = s_mp2r[rl];
            float sr   = s_sqr[rl];
            int   li   = s_labr[rl];
            float vminr = INFF;
            #pragma unroll
            for (int ni = 0; ni < 4; ++ni) {
                float d2 = fmaf(-2.0f, acc[mi][ni][v], sr + sc[ni]);
                bool neq = (li != lc[ni]);
                vminr     = fminf(vminr,     (neq && d2 > mp2r)     ? d2 : INFF);
                vminc[ni] = fminf(vminc[ni], (neq && d2 > mp2c[ni]) ? d2 : INFF);
            }
            #pragma unroll
            for (int off = 8; off; off >>= 1)
                vminr = fminf(vminr, __shfl_xor(vminr, off, 64));
            if (lm == 0 && __float_as_uint(vminr) != INF_BITS)
                atomicMin(&minbits[i0 + rl], __float_as_uint(vminr));
        }
    }
    if (!diag) {
        #pragma unroll
        for (int ni = 0; ni < 4; ++ni) {
            float vc = vminc[ni];
            vc = fminf(vc, __shfl_xor(vc, 16, 64));
            vc = fminf(vc, __shfl_xor(vc, 32, 64));
            if (ls == 0 && __float_as_uint(vc) != INF_BITS)
                atomicMin(&minbits[j0 + cw + ni * 16 + lm], __float_as_uint(vc));
        }
    }
}

// ---------------------------------------------------------------------------
// K4: final reduction (separate kernel; kernel boundary = coherence point,
// so plain loads suffice; minbits holds d2 -> sqrt here).
// ---------------------------------------------------------------------------
__global__ __launch_bounds__(1024) void k_finish(const float* __restrict__ meanpos,
        const float* __restrict__ pcinv, const int* __restrict__ poscnt,
        const unsigned* __restrict__ minbits, float* __restrict__ out, int Bn) {
    float lsum = 0.f; int lcnt = 0;
    for (int i = threadIdx.x; i < Bn; i += 1024) {
        int pc = poscnt[i];
        bool valid = (pc > 1) && (pc < Bn);
        unsigned mb = minbits[i];
        if (valid && mb != INF_BITS) {
            float v = fmaf(meanpos[i], pcinv[i], MARGIN - sqrtf(__uint_as_float(mb)));
            lsum += (v > 0.f) ? v : 0.f;
            lcnt += 1;
        }
    }
    __shared__ float ssum[16]; __shared__ int scnt[16];
    int lane = threadIdx.x & 63, wid = threadIdx.x >> 6;
    #pragma unroll
    for (int off = 32; off; off >>= 1) {
        lsum += __shfl_down(lsum, off, 64);
        lcnt += __shfl_down(lcnt, off, 64);
    }
    if (lane == 0) { ssum[wid] = lsum; scnt[wid] = lcnt; }
    __syncthreads();
    if (threadIdx.x == 0) {
        float s = 0.f; int c = 0;
        #pragma unroll
        for (int q = 0; q < 16; ++q) { s += ssum[q]; c += scnt[q]; }
        out[0] = (c > 0) ? s / (float)c : 0.f;
    }
}

// ---------------------------------------------------------------------------
extern "C" void kernel_launch(void* const* d_in, const int* in_sizes, int n_in,
                              void* d_out, int out_size, void* d_ws, size_t ws_size,
                              hipStream_t stream) {
    const float* x = (const float*)d_in[0];
    const int* lab = (const int*)d_in[1];
    int Bn = in_sizes[1];                 // 8192; D fixed at 512

    size_t nd = (size_t)(Bn + PADR) * D;  // padded for banded over-read
    unsigned short* fh = (unsigned short*)d_ws;
    float* sqp        = (float*)(fh + nd);
    float* meanpos    = sqp + Bn;         // raw dist-sums
    float* pcinv      = meanpos + Bn;
    int* poscnt       = (int*)(pcinv + Bn);
    unsigned* minbits = (unsigned*)(poscnt + Bn);
    int* pos          = (int*)(minbits + Bn);
    int* labp         = pos + Bn;
    int* cstart_g     = labp + Bn;
    int* ccnt_g       = cstart_g + NCLS;

    k_bucket<<<1, 1024, 0, stream>>>(lab, Bn, pos, labp, cstart_g, ccnt_g,
                                     meanpos, pcinv, poscnt, minbits);
    k_normalize<<<Bn / 4, 256, 0, stream>>>(x, pos, fh, sqp);
    k_posband3<<<Bn / 16, 256, 0, stream>>>(fh, sqp, labp, cstart_g, ccnt_g,
                                            meanpos, Bn);
    int nb = Bn / 128;
    int T = nb * (nb + 1) / 2;            // 2080
    k_minsh_mfma<<<T, 256, 0, stream>>>(fh, sqp, labp, meanpos, pcinv, minbits);
    k_finish<<<1, 1024, 0, stream>>>(meanpos, pcinv, poscnt, minbits,
                                     (float*)d_out, Bn);
}